// Round 4
// baseline (843.979 us; speedup 1.0000x reference)
//
#include <hip/hip_runtime.h>

// ---------------- common ----------------
typedef float  f32x4  __attribute__((ext_vector_type(4)));
typedef short  bf16x8 __attribute__((ext_vector_type(8)));
typedef unsigned short u16;
typedef unsigned int   u32;

static __device__ __forceinline__ u16 f2bf(float f) {   // RNE float -> bf16
    u32 u = __float_as_uint(f);
    u += 0x7FFFu + ((u >> 16) & 1u);
    return (u16)(u >> 16);
}

// dims: B=8 N=128 F_IN=64 F_E=16 H=256 L=8

// ---------------- setup kernels ----------------

// h0 = x @ node_W + node_b, then mask + layernorm(l=0) -> bf16.  grid: 1024 x 256
__global__ void k_h0ln(const float* __restrict__ x, const float* __restrict__ nW,
                       const float* __restrict__ nb, const int* __restrict__ mask,
                       const float* __restrict__ lng, const float* __restrict__ lnb,
                       float* __restrict__ h, u16* __restrict__ hnbf) {
    __shared__ float xr[64];
    __shared__ float rs[4], rs2[4];
    int row = blockIdx.x, c = threadIdx.x;
    if (c < 64) xr[c] = x[row * 64 + c];
    __syncthreads();
    float acc = nb[c];
#pragma unroll
    for (int k = 0; k < 64; ++k) acc += xr[k] * nW[k * 256 + c];
    float mv = (float)mask[row];
    float v = acc * mv;
    h[row * 256 + c] = v;
    float s = v, s2 = v * v;
    int w = c >> 6, lane = c & 63;
#pragma unroll
    for (int off = 32; off; off >>= 1) {
        s  += __shfl_xor(s,  off);
        s2 += __shfl_xor(s2, off);
    }
    if (lane == 0) { rs[w] = s; rs2[w] = s2; }
    __syncthreads();
    float S  = rs[0] + rs[1] + rs[2] + rs[3];
    float S2 = rs2[0] + rs2[1] + rs2[2] + rs2[3];
    float mu  = S * (1.f / 256.f);
    float var = S2 * (1.f / 256.f) - mu * mu;
    float rstd = rsqrtf(var + 1e-5f);
    hnbf[row * 256 + c] = f2bf((v - mu) * rstd * lng[c] + lnb[c]);
}

// edge_attr -> bf16 fragment layout, K padded 16->32 with zeros.
__global__ void k_edgefrag(const float* __restrict__ ea, u16* __restrict__ ef) {
    int gid = blockIdx.x * 256 + threadIdx.x;
    int lane = gid & 63, nt = (gid >> 6) & 7, i = (gid >> 9) & 127, b = gid >> 16;
    int j = nt * 16 + (lane & 15), k0 = (lane >> 4) * 8;
    uint4 out = {0u, 0u, 0u, 0u};
    if (k0 < 16) {
        const float* p = ea + (((size_t)(b * 128 + i) * 128 + j) * 16 + k0);
        u16 us[8];
#pragma unroll
        for (int t = 0; t < 8; ++t) us[t] = f2bf(p[t]);
        out.x = (u32)us[0] | ((u32)us[1] << 16);
        out.y = (u32)us[2] | ((u32)us[3] << 16);
        out.z = (u32)us[4] | ((u32)us[5] << 16);
        out.w = (u32)us[6] | ((u32)us[7] << 16);
    }
    ((uint4*)ef)[gid] = out;
}

// W1^T / W2^T fragment packs: wt[((l*8+kt)*16+mt)*64+lane][8]
__global__ void k_wt(const float* __restrict__ W1, const float* __restrict__ W2,
                     u16* __restrict__ w1t, u16* __restrict__ w2t) {
    int gid = blockIdx.x * 256 + threadIdx.x;
    int lane = gid & 63, mt = (gid >> 6) & 15, kt = (gid >> 10) & 7, l = gid >> 13;
    int hh = mt * 16 + (lane & 15), k = kt * 32 + (lane >> 4) * 8;
    u16 a[8], b[8];
#pragma unroll
    for (int t = 0; t < 8; ++t) {
        size_t idx = (size_t)l * 65536 + (size_t)(k + t) * 256 + hh;
        a[t] = f2bf(W1[idx]);
        b[t] = f2bf(W2[idx]);
    }
    uint4 oa, ob;
    oa.x = (u32)a[0] | ((u32)a[1] << 16); oa.y = (u32)a[2] | ((u32)a[3] << 16);
    oa.z = (u32)a[4] | ((u32)a[5] << 16); oa.w = (u32)a[6] | ((u32)a[7] << 16);
    ob.x = (u32)b[0] | ((u32)b[1] << 16); ob.y = (u32)b[2] | ((u32)b[3] << 16);
    ob.z = (u32)b[4] | ((u32)b[5] << 16); ob.w = (u32)b[6] | ((u32)b[7] << 16);
    ((uint4*)w1t)[gid] = oa;
    ((uint4*)w2t)[gid] = ob;
}

// ro_pW^T fragment pack: pwt[(kt*16+mt)*64+lane][8]   grid: 32 x 256
__global__ void k_pwt(const float* __restrict__ pW, u16* __restrict__ pwt) {
    int gid = blockIdx.x * 256 + threadIdx.x;
    int lane = gid & 63, mt = (gid >> 6) & 15, kt = gid >> 10;
    int hh = mt * 16 + (lane & 15), k = kt * 32 + (lane >> 4) * 8;
    u16 a[8];
#pragma unroll
    for (int t = 0; t < 8; ++t) a[t] = f2bf(pW[(size_t)(k + t) * 256 + hh]);
    uint4 o;
    o.x = (u32)a[0] | ((u32)a[1] << 16); o.y = (u32)a[2] | ((u32)a[3] << 16);
    o.z = (u32)a[4] | ((u32)a[5] << 16); o.w = (u32)a[6] | ((u32)a[7] << 16);
    ((uint4*)pwt)[gid] = o;
}

// Wf1 = edge_W @ W1[l] (A-fragment pack) AND bias1 = edge_b @ W1[l] + b1[l]
__global__ void k_wf1b(const float* __restrict__ eW, const float* __restrict__ eb,
                       const float* __restrict__ W1, const float* __restrict__ b1,
                       u16* __restrict__ wf, float* __restrict__ bias1) {
    __shared__ float eWsT[256 * 16];   // [c][k]
    __shared__ float ebS[256];
    int l = blockIdx.x, tid = threadIdx.x;
#pragma unroll
    for (int k = 0; k < 16; ++k) eWsT[tid * 16 + k] = eW[k * 256 + tid];
    ebS[tid] = eb[tid];
    __syncthreads();
    float acc[16];
#pragma unroll
    for (int k = 0; k < 16; ++k) acc[k] = 0.f;
    float bacc = b1[l * 256 + tid];
    const float* w1c = W1 + (size_t)l * 65536 + tid;
    for (int c = 0; c < 256; ++c) {
        float wv = w1c[(size_t)c * 256];
        const f32x4* e = (const f32x4*)&eWsT[c * 16];
#pragma unroll
        for (int q = 0; q < 4; ++q) {
            f32x4 ev = e[q];
#pragma unroll
            for (int t = 0; t < 4; ++t) acc[q * 4 + t] += ev[t] * wv;
        }
        bacc += ebS[c] * wv;
    }
    bias1[l * 256 + tid] = bacc;
    int mt = tid >> 4, lo = tid & 15;
#pragma unroll
    for (int c4 = 0; c4 < 4; ++c4) {
        u16 us[8];
#pragma unroll
        for (int t = 0; t < 8; ++t) {
            int k = c4 * 8 + t;
            us[t] = (k < 16) ? f2bf(acc[k]) : (u16)0;
        }
        uint4 o;
        o.x = (u32)us[0] | ((u32)us[1] << 16);
        o.y = (u32)us[2] | ((u32)us[3] << 16);
        o.z = (u32)us[4] | ((u32)us[5] << 16);
        o.w = (u32)us[6] | ((u32)us[7] << 16);
        ((uint4*)wf)[(size_t)(l * 16 + mt) * 64 + c4 * 16 + lo] = o;
    }
}

// ---------------- per-layer kernels ----------------

// hn1' = h_norm @ W1[l] + bias1[l] (transposed, fragment-permuted output)
// grid: 128 x 256  (block = (b, mt))
__global__ __launch_bounds__(256) void k_hn1(const u16* __restrict__ w1t,
        const u16* __restrict__ hnbf, const float* __restrict__ bias1,
        float* __restrict__ hn1p, int l) {
    int orig = blockIdx.x;
    int bid = (orig & 7) * 16 + (orig >> 3);      // XCD swizzle
    int b = bid >> 4, mt = bid & 15;
    int tid = threadIdx.x, w = tid >> 6, lane = tid & 63;
    f32x4 bv = *(const f32x4*)(bias1 + l * 256 + mt * 16 + (lane >> 4) * 4);
    f32x4 acc0 = bv, acc1 = bv;
    int j0 = (w * 2) * 16 + (lane & 15), j1 = j0 + 16;
#pragma unroll
    for (int kt = 0; kt < 8; ++kt) {
        bf16x8 a = *(const bf16x8*)(w1t + ((size_t)((l * 8 + kt) * 16 + mt) * 64 + lane) * 8);
        bf16x8 bt0 = *(const bf16x8*)(hnbf + ((size_t)(b * 128 + j0) * 256 + kt * 32 + (lane >> 4) * 8));
        bf16x8 bt1 = *(const bf16x8*)(hnbf + ((size_t)(b * 128 + j1) * 256 + kt * 32 + (lane >> 4) * 8));
        acc0 = __builtin_amdgcn_mfma_f32_16x16x32_bf16(a, bt0, acc0, 0, 0, 0);
        acc1 = __builtin_amdgcn_mfma_f32_16x16x32_bf16(a, bt1, acc1, 0, 0, 0);
    }
    float* outb = hn1p + (size_t)b * 32768;
    *(f32x4*)(outb + ((size_t)(mt * 8 + w * 2) * 64 + lane) * 4)     = acc0;
    *(f32x4*)(outb + ((size_t)(mt * 8 + w * 2 + 1) * 64 + lane) * 4) = acc1;
}

// money kernel: active-j compaction + T1=relu(edge@Wf1+hn1'), T2=relu(T1@W2+b2),
// msg=sum_act T2; h=(h+msg)*m; emits bf16 rows (LN'd or raw) for next stage.
// waves: mq = w&3 owns mt-quad, ng = w>>2 owns n-parity  (4-mt reuse per ds_read)
// grid: 1024 x 512, 2 blocks/CU
__global__ __launch_bounds__(512, 4) void k_msg(
        const u16* __restrict__ wf1t, const u16* __restrict__ ef,
        const u16* __restrict__ w2t,  const float* __restrict__ hn1p,
        const float* __restrict__ b2, const int* __restrict__ adj,
        const int* __restrict__ mask, float* __restrict__ h,
        const float* __restrict__ lngN, const float* __restrict__ lnbN,
        u16* __restrict__ hnbf, int l, int doLN) {

    __shared__ __align__(16) u16  t1S[8 * 8 * 64 * 8];   // 64 KiB [kt2][n][lane][8]
    __shared__ __align__(16) float b2S[256];
    __shared__ __align__(16) float msgS[2][256];
    __shared__ int listS[128];
    __shared__ int cntS;
    __shared__ float rs[8], rs2[8];

    int orig = blockIdx.x;
    int bid = (orig & 7) * 128 + (orig >> 3);     // XCD swizzle
    int b = bid >> 7, i = bid & 127;
    int tid = threadIdx.x, w = tid >> 6, lane = tid & 63;
    int mq = w & 3, ng = w >> 2;
    int row = b * 128 + i;

    if (tid < 256) b2S[tid] = b2[l * 256 + tid];
    if (w == 0) {   // active-j compaction (order-preserving), one wave
        listS[lane] = 0; listS[64 + lane] = 0;
        int f0 = adj[(size_t)row * 128 + lane];
        int f1 = adj[(size_t)row * 128 + 64 + lane];
        unsigned long long m0 = __ballot(f0 != 0);
        unsigned long long m1 = __ballot(f1 != 0);
        unsigned long long lt = (1ull << lane) - 1ull;
        int c0 = __popcll(m0);
        if (f0) listS[__popcll(m0 & lt)] = lane;
        if (f1) listS[c0 + __popcll(m1 & lt)] = 64 + lane;
        if (lane == 0) cntS = c0 + __popcll(m1);
    }
    __syncthreads();
    int cnt = cntS;
    int NT = (cnt + 15) >> 4;

    // ---- GEMM1 on active tiles: T1^T = Wf1^T(256x32) @ edge^T(32x|act|)
    const u16*  efb = ef + (size_t)row * 4096;
    const float* hpb = hn1p + (size_t)b * 32768;
    bf16x8 aG[4];
#pragma unroll
    for (int m = 0; m < 4; ++m)
        aG[m] = *(const bf16x8*)(wf1t + ((size_t)(l * 16 + mq * 4 + m) * 64 + lane) * 8);
    for (int n = ng; n < NT; n += 2) {
        int j = listS[n * 16 + (lane & 15)];
        int jo = (j >> 4) * 64 + (lane & 48) + (j & 15);
        bf16x8 be = *(const bf16x8*)(efb + (size_t)jo * 8);
#pragma unroll
        for (int m = 0; m < 4; ++m) {
            int mt = mq * 4 + m;
            f32x4 ci = *(const f32x4*)(hpb + ((size_t)(mt * 8) * 64 + jo) * 4);
            f32x4 acc = __builtin_amdgcn_mfma_f32_16x16x32_bf16(aG[m], be, ci, 0, 0, 0);
            u32 lo = (u32)f2bf(fmaxf(acc[0], 0.f)) | ((u32)f2bf(fmaxf(acc[1], 0.f)) << 16);
            u32 hi = (u32)f2bf(fmaxf(acc[2], 0.f)) | ((u32)f2bf(fmaxf(acc[3], 0.f)) << 16);
            int g = ((mt & 1) << 1) | (lane >> 5), half = (lane >> 4) & 1;
            uint2 pk; pk.x = lo; pk.y = hi;
            *(uint2*)(t1S + ((size_t)(((mt >> 1) * 8 + n) * 64) + g * 16 + (lane & 15)) * 8 + half * 4) = pk;
        }
    }
    __syncthreads();

    // ---- GEMM2: T2^T = W2^T(256x256) @ T1^T ; each ds_read feeds 4 MFMA
    f32x4 bv[4], ms[4];
#pragma unroll
    for (int m = 0; m < 4; ++m) {
        bv[m] = *(const f32x4*)(&b2S[(mq * 4 + m) * 16 + (lane >> 4) * 4]);
        ms[m] = (f32x4){0.f, 0.f, 0.f, 0.f};
    }
    for (int n = ng; n < NT; n += 2) {
        f32x4 acc[4];
#pragma unroll
        for (int m = 0; m < 4; ++m) acc[m] = (f32x4){0.f, 0.f, 0.f, 0.f};
#pragma unroll
        for (int kt = 0; kt < 8; ++kt) {
            bf16x8 bt = *(const bf16x8*)(t1S + ((size_t)(kt * 8 + n) * 64 + lane) * 8);
#pragma unroll
            for (int m = 0; m < 4; ++m) {
                bf16x8 a2 = *(const bf16x8*)(w2t + ((size_t)((l * 8 + kt) * 16 + mq * 4 + m) * 64 + lane) * 8);
                acc[m] = __builtin_amdgcn_mfma_f32_16x16x32_bf16(a2, bt, acc[m], 0, 0, 0);
            }
        }
        float aw = (n * 16 + (lane & 15)) < cnt ? 1.f : 0.f;
#pragma unroll
        for (int m = 0; m < 4; ++m)
#pragma unroll
            for (int r = 0; r < 4; ++r)
                ms[m][r] += fmaxf(acc[m][r] + bv[m][r], 0.f) * aw;
    }
#pragma unroll
    for (int m = 0; m < 4; ++m)
#pragma unroll
        for (int r = 0; r < 4; ++r) {
            ms[m][r] += __shfl_xor(ms[m][r], 1);
            ms[m][r] += __shfl_xor(ms[m][r], 2);
            ms[m][r] += __shfl_xor(ms[m][r], 4);
            ms[m][r] += __shfl_xor(ms[m][r], 8);
        }
    if ((lane & 15) == 0) {
#pragma unroll
        for (int m = 0; m < 4; ++m)
            *(f32x4*)(&msgS[ng][(mq * 4 + m) * 16 + (lane >> 4) * 4]) = ms[m];
    }
    __syncthreads();

    // ---- tail: residual + mask; always emit bf16 rows (LN'd or raw)
    float v = 0.f;
    if (tid < 256) {
        float mv = (float)mask[row];
        v = (h[(size_t)row * 256 + tid] + msgS[0][tid] + msgS[1][tid]) * mv;
        h[(size_t)row * 256 + tid] = v;
    }
    float s = v, s2 = v * v;
#pragma unroll
    for (int off = 32; off; off >>= 1) {
        s  += __shfl_xor(s,  off);
        s2 += __shfl_xor(s2, off);
    }
    if (lane == 0) { rs[w] = s; rs2[w] = s2; }
    __syncthreads();
    if (tid < 256) {
        float o;
        if (doLN) {
            float S = 0.f, S2 = 0.f;
#pragma unroll
            for (int t = 0; t < 8; ++t) { S += rs[t]; S2 += rs2[t]; }
            float mu  = S * (1.f / 256.f);
            float var = S2 * (1.f / 256.f) - mu * mu;
            float rstd = rsqrtf(var + 1e-5f);
            o = (v - mu) * rstd * lngN[tid] + lnbN[tid];
        } else o = v;
        hnbf[(size_t)row * 256 + tid] = f2bf(o);
    }
}

// ---------------- readout ----------------

// scores = tanh(h@pW+pb)@aW + ab via MFMA on raw bf16 h rows.  grid: 8 x 512
__global__ __launch_bounds__(512) void k_ro1(const u16* __restrict__ hbf,
        const u16* __restrict__ pwt, const float* __restrict__ pb,
        const float* __restrict__ aW, const float* __restrict__ ab,
        float* __restrict__ scores) {
    int b = blockIdx.x;
    int tid = threadIdx.x, w = tid >> 6, lane = tid & 63;
    f32x4 acc[16];
#pragma unroll
    for (int mt = 0; mt < 16; ++mt)
        acc[mt] = *(const f32x4*)(pb + mt * 16 + (lane >> 4) * 4);
#pragma unroll
    for (int kt = 0; kt < 8; ++kt) {
        bf16x8 bt = *(const bf16x8*)(hbf + ((size_t)(b * 128 + w * 16 + (lane & 15)) * 256 + kt * 32 + (lane >> 4) * 8));
#pragma unroll
        for (int mt = 0; mt < 16; ++mt) {
            bf16x8 a = *(const bf16x8*)(pwt + ((size_t)(kt * 16 + mt) * 64 + lane) * 8);
            acc[mt] = __builtin_amdgcn_mfma_f32_16x16x32_bf16(a, bt, acc[mt], 0, 0, 0);
        }
    }
    float sc = 0.f;
#pragma unroll
    for (int mt = 0; mt < 16; ++mt) {
#pragma unroll
        for (int r = 0; r < 4; ++r)
            sc += tanhf(acc[mt][r]) * aW[mt * 16 + (lane >> 4) * 4 + r];
    }
    sc += __shfl_xor(sc, 16);
    sc += __shfl_xor(sc, 32);
    if (lane < 16) scores[b * 128 + w * 16 + lane] = sc + ab[0];
}

__global__ void k_ro2(const float* __restrict__ h, const float* __restrict__ scores,
                      const int* __restrict__ mask, const float* __restrict__ phW,
                      const float* __restrict__ phb, float* __restrict__ out) {
    __shared__ float aS[128];
    __shared__ float rm[4], rc[4], red[4];
    int b = blockIdx.x, tid = threadIdx.x, w = tid >> 6, lane = tid & 63;
    float mv = 0.f, sv = -__builtin_inff();
    if (tid < 128) {
        mv = (float)mask[b * 128 + tid];
        if (mv > 0.f) sv = scores[b * 128 + tid];
    }
    float mx = sv, cs = mv;
#pragma unroll
    for (int off = 32; off; off >>= 1) {
        mx = fmaxf(mx, __shfl_xor(mx, off));
        cs += __shfl_xor(cs, off);
    }
    if (lane == 0) { rm[w] = mx; rc[w] = cs; }
    __syncthreads();
    mx = fmaxf(fmaxf(rm[0], rm[1]), fmaxf(rm[2], rm[3]));
    float cnt = rc[0] + rc[1] + rc[2] + rc[3];
    float e = (tid < 128 && mv > 0.f) ? expf(sv - mx) : 0.f;
    float se = e;
#pragma unroll
    for (int off = 32; off; off >>= 1) se += __shfl_xor(se, off);
    if (lane == 0) red[w] = se;
    __syncthreads();
    float S = red[0] + red[1] + red[2] + red[3];
    if (tid < 128) {
        float a;
        if (S > 0.f) a = e / S;
        else         a = (mv > 0.f) ? 1.f / fmaxf(cnt, 1.f) : 0.f;
        aS[tid] = a;
    }
    __syncthreads();
    float g = 0.f;
    const float* hb = h + (size_t)b * 128 * 256;
    for (int n = 0; n < 128; ++n) g += aS[n] * hb[(size_t)n * 256 + tid];
    float p = g * phW[tid];
#pragma unroll
    for (int off = 32; off; off >>= 1) p += __shfl_xor(p, off);
    __syncthreads();
    if (lane == 0) red[w] = p;
    __syncthreads();
    if (tid == 0) out[b] = red[0] + red[1] + red[2] + red[3] + phb[0];
}

// ---------------- host ----------------
extern "C" void kernel_launch(void* const* d_in, const int* in_sizes, int n_in,
                              void* d_out, int out_size, void* d_ws, size_t ws_size,
                              hipStream_t stream) {
    const float* x    = (const float*)d_in[0];
    const int*   adj  = (const int*)  d_in[1];
    const float* ea   = (const float*)d_in[2];
    const int*   mask = (const int*)  d_in[3];
    const float* nW   = (const float*)d_in[4];
    const float* nb   = (const float*)d_in[5];
    const float* eW   = (const float*)d_in[6];
    const float* eb   = (const float*)d_in[7];
    const float* lng  = (const float*)d_in[8];
    const float* lnb  = (const float*)d_in[9];
    const float* W1   = (const float*)d_in[10];
    const float* b1   = (const float*)d_in[11];
    const float* W2   = (const float*)d_in[12];
    const float* b2   = (const float*)d_in[13];
    const float* ropW = (const float*)d_in[14];
    const float* ropb = (const float*)d_in[15];
    const float* roaW = (const float*)d_in[16];
    const float* roab = (const float*)d_in[17];
    const float* phW  = (const float*)d_in[18];
    const float* phb  = (const float*)d_in[19];
    float* out = (float*)d_out;

    char* p = (char*)d_ws;
    auto alloc = [&](size_t bytes) { char* r = p; p += (bytes + 255) & ~(size_t)255; return r; };
    float* h     = (float*)alloc((size_t)8 * 128 * 256 * 4);
    u16*   hnbf  = (u16*)  alloc((size_t)8 * 128 * 256 * 2);
    float* hn1p  = (float*)alloc((size_t)8 * 32768 * 4);
    u16*   ef    = (u16*)  alloc((size_t)8 * 128 * 4096 * 2);
    u16*   wf1t  = (u16*)  alloc((size_t)8 * 16 * 64 * 8 * 2);
    u16*   w1t   = (u16*)  alloc((size_t)8 * 8 * 16 * 64 * 8 * 2);
    u16*   w2t   = (u16*)  alloc((size_t)8 * 8 * 16 * 64 * 8 * 2);
    u16*   pwt   = (u16*)  alloc((size_t)8 * 16 * 64 * 8 * 2);
    float* bias1 = (float*)alloc((size_t)8 * 256 * 4);
    float* scores= (float*)alloc((size_t)1024 * 4);

    k_h0ln    <<<1024, 256, 0, stream>>>(x, nW, nb, mask, lng, lnb, h, hnbf);
    k_edgefrag<<<2048, 256, 0, stream>>>(ea, ef);
    k_wt      <<<256,  256, 0, stream>>>(W1, W2, w1t, w2t);
    k_wf1b    <<<8,    256, 0, stream>>>(eW, eb, W1, b1, wf1t, bias1);
    k_pwt     <<<32,   256, 0, stream>>>(ropW, pwt);

    for (int l = 0; l < 8; ++l) {
        k_hn1<<<128,  256, 0, stream>>>(w1t, hnbf, bias1, hn1p, l);
        int doLN = (l < 7) ? 1 : 0;
        int ln_next = (l < 7) ? (l + 1) : l;
        k_msg<<<1024, 512, 0, stream>>>(wf1t, ef, w2t, hn1p, b2, adj, mask, h,
                                        lng + ln_next * 256, lnb + ln_next * 256,
                                        hnbf, l, doLN);
    }

    k_ro1<<<8,   512, 0, stream>>>(hnbf, pwt, ropb, roaW, roab, scores);
    k_ro2<<<8,   256, 0, stream>>>(h, scores, mask, phW, phb, out);
}

// Round 5
// 415.726 us; speedup vs baseline: 2.0301x; 2.0301x over previous
//
#include <hip/hip_runtime.h>

// ---------------- common ----------------
typedef float  f32x4   __attribute__((ext_vector_type(4)));
typedef float  f32x16  __attribute__((ext_vector_type(16)));
typedef short  bf16x8  __attribute__((ext_vector_type(8)));
typedef unsigned short u16;
typedef unsigned int   u32;

static __device__ __forceinline__ u16 f2bf(float f) {   // RNE float -> bf16
    u32 u = __float_as_uint(f);
    u += 0x7FFFu + ((u >> 16) & 1u);
    return (u16)(u >> 16);
}

// dims: B=8 N=128 F_IN=64 F_E=16 H=256 L=8

// ---------------- setup kernels ----------------

// h0 = x @ node_W + node_b, then mask + layernorm(l=0) -> bf16.  grid: 1024 x 256
__global__ void k_h0ln(const float* __restrict__ x, const float* __restrict__ nW,
                       const float* __restrict__ nb, const int* __restrict__ mask,
                       const float* __restrict__ lng, const float* __restrict__ lnb,
                       float* __restrict__ h, u16* __restrict__ hnbf) {
    __shared__ float xr[64];
    __shared__ float rs[4], rs2[4];
    int row = blockIdx.x, c = threadIdx.x;
    if (c < 64) xr[c] = x[row * 64 + c];
    __syncthreads();
    float acc = nb[c];
#pragma unroll
    for (int k = 0; k < 64; ++k) acc += xr[k] * nW[k * 256 + c];
    float mv = (float)mask[row];
    float v = acc * mv;
    h[row * 256 + c] = v;
    float s = v, s2 = v * v;
    int w = c >> 6, lane = c & 63;
#pragma unroll
    for (int off = 32; off; off >>= 1) {
        s  += __shfl_xor(s,  off);
        s2 += __shfl_xor(s2, off);
    }
    if (lane == 0) { rs[w] = s; rs2[w] = s2; }
    __syncthreads();
    float S  = rs[0] + rs[1] + rs[2] + rs[3];
    float S2 = rs2[0] + rs2[1] + rs2[2] + rs2[3];
    float mu  = S * (1.f / 256.f);
    float var = S2 * (1.f / 256.f) - mu * mu;
    float rstd = rsqrtf(var + 1e-5f);
    hnbf[row * 256 + c] = f2bf((v - mu) * rstd * lng[c] + lnb[c]);
}

// edge_attr -> bf16 fragment layout (16x16x32 A/B style), K padded 16->32.
__global__ void k_edgefrag(const float* __restrict__ ea, u16* __restrict__ ef) {
    int gid = blockIdx.x * 256 + threadIdx.x;
    int lane = gid & 63, nt = (gid >> 6) & 7, i = (gid >> 9) & 127, b = gid >> 16;
    int j = nt * 16 + (lane & 15), k0 = (lane >> 4) * 8;
    uint4 out = {0u, 0u, 0u, 0u};
    if (k0 < 16) {
        const float* p = ea + (((size_t)(b * 128 + i) * 128 + j) * 16 + k0);
        u16 us[8];
#pragma unroll
        for (int t = 0; t < 8; ++t) us[t] = f2bf(p[t]);
        out.x = (u32)us[0] | ((u32)us[1] << 16);
        out.y = (u32)us[2] | ((u32)us[3] << 16);
        out.z = (u32)us[4] | ((u32)us[5] << 16);
        out.w = (u32)us[6] | ((u32)us[7] << 16);
    }
    ((uint4*)ef)[gid] = out;
}

// W1^T fragment pack (16x16x32 A): w1t[((l*8+kt)*16+mt)*64+lane][8]
__global__ void k_wt(const float* __restrict__ W1, u16* __restrict__ w1t) {
    int gid = blockIdx.x * 256 + threadIdx.x;
    int lane = gid & 63, mt = (gid >> 6) & 15, kt = (gid >> 10) & 7, l = gid >> 13;
    int hh = mt * 16 + (lane & 15), k = kt * 32 + (lane >> 4) * 8;
    u16 a[8];
#pragma unroll
    for (int t = 0; t < 8; ++t)
        a[t] = f2bf(W1[(size_t)l * 65536 + (size_t)(k + t) * 256 + hh]);
    uint4 oa;
    oa.x = (u32)a[0] | ((u32)a[1] << 16); oa.y = (u32)a[2] | ((u32)a[3] << 16);
    oa.z = (u32)a[4] | ((u32)a[5] << 16); oa.w = (u32)a[6] | ((u32)a[7] << 16);
    ((uint4*)w1t)[gid] = oa;
}

// W2^T pack in 32x32x16 A-fragment layout:
// w2t32[((l*16+ks)*8+m)*64+lane][8] = W2[l][hin=ks*16+(lane>>5)*8+t][hout=m*32+(lane&31)]
__global__ void k_w2t32(const float* __restrict__ W2, u16* __restrict__ w2t) {
    int gid = blockIdx.x * 256 + threadIdx.x;
    int lane = gid & 63, m = (gid >> 6) & 7, ks = (gid >> 9) & 15, l = gid >> 13;
    int hout = m * 32 + (lane & 31), hin = ks * 16 + (lane >> 5) * 8;
    u16 a[8];
#pragma unroll
    for (int t = 0; t < 8; ++t)
        a[t] = f2bf(W2[(size_t)l * 65536 + (size_t)(hin + t) * 256 + hout]);
    uint4 oa;
    oa.x = (u32)a[0] | ((u32)a[1] << 16); oa.y = (u32)a[2] | ((u32)a[3] << 16);
    oa.z = (u32)a[4] | ((u32)a[5] << 16); oa.w = (u32)a[6] | ((u32)a[7] << 16);
    ((uint4*)w2t)[gid] = oa;
}

// ro_pW^T fragment pack (16x16x32 A): pwt[(kt*16+mt)*64+lane][8]
__global__ void k_pwt(const float* __restrict__ pW, u16* __restrict__ pwt) {
    int gid = blockIdx.x * 256 + threadIdx.x;
    int lane = gid & 63, mt = (gid >> 6) & 15, kt = gid >> 10;
    int hh = mt * 16 + (lane & 15), k = kt * 32 + (lane >> 4) * 8;
    u16 a[8];
#pragma unroll
    for (int t = 0; t < 8; ++t) a[t] = f2bf(pW[(size_t)(k + t) * 256 + hh]);
    uint4 o;
    o.x = (u32)a[0] | ((u32)a[1] << 16); o.y = (u32)a[2] | ((u32)a[3] << 16);
    o.z = (u32)a[4] | ((u32)a[5] << 16); o.w = (u32)a[6] | ((u32)a[7] << 16);
    ((uint4*)pwt)[gid] = o;
}

// Wf1 = edge_W @ W1[l] (A-fragment pack) AND bias1 = edge_b @ W1[l] + b1[l]
__global__ void k_wf1b(const float* __restrict__ eW, const float* __restrict__ eb,
                       const float* __restrict__ W1, const float* __restrict__ b1,
                       u16* __restrict__ wf, float* __restrict__ bias1) {
    __shared__ float eWsT[256 * 16];   // [c][k]
    __shared__ float ebS[256];
    int l = blockIdx.x, tid = threadIdx.x;
#pragma unroll
    for (int k = 0; k < 16; ++k) eWsT[tid * 16 + k] = eW[k * 256 + tid];
    ebS[tid] = eb[tid];
    __syncthreads();
    float acc[16];
#pragma unroll
    for (int k = 0; k < 16; ++k) acc[k] = 0.f;
    float bacc = b1[l * 256 + tid];
    const float* w1c = W1 + (size_t)l * 65536 + tid;
    for (int c = 0; c < 256; ++c) {
        float wv = w1c[(size_t)c * 256];
        const f32x4* e = (const f32x4*)&eWsT[c * 16];
#pragma unroll
        for (int q = 0; q < 4; ++q) {
            f32x4 ev = e[q];
#pragma unroll
            for (int t = 0; t < 4; ++t) acc[q * 4 + t] += ev[t] * wv;
        }
        bacc += ebS[c] * wv;
    }
    bias1[l * 256 + tid] = bacc;
    int mt = tid >> 4, lo = tid & 15;
#pragma unroll
    for (int c4 = 0; c4 < 4; ++c4) {
        u16 us[8];
#pragma unroll
        for (int t = 0; t < 8; ++t) {
            int k = c4 * 8 + t;
            us[t] = (k < 16) ? f2bf(acc[k]) : (u16)0;
        }
        uint4 o;
        o.x = (u32)us[0] | ((u32)us[1] << 16);
        o.y = (u32)us[2] | ((u32)us[3] << 16);
        o.z = (u32)us[4] | ((u32)us[5] << 16);
        o.w = (u32)us[6] | ((u32)us[7] << 16);
        ((uint4*)wf)[(size_t)(l * 16 + mt) * 64 + c4 * 16 + lo] = o;
    }
}

// ---------------- per-layer kernels ----------------

// hn1' = h_norm @ W1[l] + bias1[l] (transposed, 16x16 fragment-permuted output)
// grid: 128 x 256  (block = (b, mt))
__global__ __launch_bounds__(256) void k_hn1(const u16* __restrict__ w1t,
        const u16* __restrict__ hnbf, const float* __restrict__ bias1,
        float* __restrict__ hn1p, int l) {
    int orig = blockIdx.x;
    int bid = (orig & 7) * 16 + (orig >> 3);      // XCD swizzle
    int b = bid >> 4, mt = bid & 15;
    int tid = threadIdx.x, w = tid >> 6, lane = tid & 63;
    f32x4 bv = *(const f32x4*)(bias1 + l * 256 + mt * 16 + (lane >> 4) * 4);
    f32x4 acc0 = bv, acc1 = bv;
    int j0 = (w * 2) * 16 + (lane & 15), j1 = j0 + 16;
#pragma unroll
    for (int kt = 0; kt < 8; ++kt) {
        bf16x8 a = *(const bf16x8*)(w1t + ((size_t)((l * 8 + kt) * 16 + mt) * 64 + lane) * 8);
        bf16x8 bt0 = *(const bf16x8*)(hnbf + ((size_t)(b * 128 + j0) * 256 + kt * 32 + (lane >> 4) * 8));
        bf16x8 bt1 = *(const bf16x8*)(hnbf + ((size_t)(b * 128 + j1) * 256 + kt * 32 + (lane >> 4) * 8));
        acc0 = __builtin_amdgcn_mfma_f32_16x16x32_bf16(a, bt0, acc0, 0, 0, 0);
        acc1 = __builtin_amdgcn_mfma_f32_16x16x32_bf16(a, bt1, acc1, 0, 0, 0);
    }
    float* outb = hn1p + (size_t)b * 32768;
    *(f32x4*)(outb + ((size_t)(mt * 8 + w * 2) * 64 + lane) * 4)     = acc0;
    *(f32x4*)(outb + ((size_t)(mt * 8 + w * 2 + 1) * 64 + lane) * 4) = acc1;
}

// money kernel: active-j compaction; GEMM1 (16x16x32) writes T1 into 32x32
// B-fragment order in LDS; GEMM2 (32x32x16) consumes it with half the LDS reads.
// grid: 1024 x 512, 2 blocks/CU
__global__ __launch_bounds__(512, 4) void k_msg(
        const u16* __restrict__ wf1t, const u16* __restrict__ ef,
        const u16* __restrict__ w2t,  const float* __restrict__ hn1p,
        const float* __restrict__ b2, const int* __restrict__ adj,
        const int* __restrict__ mask, float* __restrict__ h,
        const float* __restrict__ lngN, const float* __restrict__ lnbN,
        u16* __restrict__ hnbf, int l, int doLN) {

    __shared__ __align__(16) u16  t1S[4 * 16 * 64 * 8];  // 64 KiB, [n2][kt][lane][8]
    __shared__ __align__(16) float b2S[256];
    __shared__ __align__(16) float msgS[256];
    __shared__ int listS[128];
    __shared__ int cntS;
    __shared__ float rs[8], rs2[8];

    int orig = blockIdx.x;
    int bid = (orig & 7) * 128 + (orig >> 3);     // XCD swizzle
    int b = bid >> 7, i = bid & 127;
    int tid = threadIdx.x, w = tid >> 6, lane = tid & 63;
    int row = b * 128 + i;

    if (tid < 256) b2S[tid] = b2[l * 256 + tid];
    if (w == 0) {   // active-j compaction (order-preserving), one wave
        listS[lane] = 0; listS[64 + lane] = 0;
        int f0 = adj[(size_t)row * 128 + lane];
        int f1 = adj[(size_t)row * 128 + 64 + lane];
        unsigned long long m0 = __ballot(f0 != 0);
        unsigned long long m1 = __ballot(f1 != 0);
        unsigned long long lt = (1ull << lane) - 1ull;
        int c0 = __popcll(m0);
        if (f0) listS[__popcll(m0 & lt)] = lane;
        if (f1) listS[c0 + __popcll(m1 & lt)] = 64 + lane;
        if (lane == 0) cntS = c0 + __popcll(m1);
    }
    __syncthreads();
    int cnt = cntS;
    int NT2 = (cnt + 31) >> 5;     // 32-col tiles for GEMM2
    int NTW = NT2 * 2;             // 16-col tiles GEMM1 must fill

    // ---- GEMM1: T1^T = Wf1^T(256x32) @ edge^T(32x|act|); wave w: mt {2w,2w+1}
    const u16*  efb = ef + (size_t)row * 4096;
    const float* hpb = hn1p + (size_t)b * 32768;
    int mt0 = w * 2, mt1 = w * 2 + 1;
    bf16x8 aG0 = *(const bf16x8*)(wf1t + ((size_t)(l * 16 + mt0) * 64 + lane) * 8);
    bf16x8 aG1 = *(const bf16x8*)(wf1t + ((size_t)(l * 16 + mt1) * 64 + lane) * 8);
    // dest mapping into 32x32 B-frag order:
    int dlane = ((lane >> 5) << 5) | (lane & 15);          // + (nt&1)<<4 per-iter
    int toff  = ((lane >> 4) & 1) * 4;                     // u16 offset within lane slot
    for (int nt = 0; nt < NTW; ++nt) {
        int j = listS[nt * 16 + (lane & 15)];
        int jo = (j >> 4) * 64 + (lane & 48) + (j & 15);
        bf16x8 be = *(const bf16x8*)(efb + (size_t)jo * 8);
        int n2 = nt >> 1;
        int dl = dlane | ((nt & 1) << 4);
        {
            f32x4 ci = *(const f32x4*)(hpb + ((size_t)(mt0 * 8) * 64 + jo) * 4);
            f32x4 acc = __builtin_amdgcn_mfma_f32_16x16x32_bf16(aG0, be, ci, 0, 0, 0);
            uint2 pk;
            pk.x = (u32)f2bf(fmaxf(acc[0], 0.f)) | ((u32)f2bf(fmaxf(acc[1], 0.f)) << 16);
            pk.y = (u32)f2bf(fmaxf(acc[2], 0.f)) | ((u32)f2bf(fmaxf(acc[3], 0.f)) << 16);
            *(uint2*)(t1S + ((size_t)((n2 * 16 + mt0) * 64 + dl) * 8 + toff)) = pk;
        }
        {
            f32x4 ci = *(const f32x4*)(hpb + ((size_t)(mt1 * 8) * 64 + jo) * 4);
            f32x4 acc = __builtin_amdgcn_mfma_f32_16x16x32_bf16(aG1, be, ci, 0, 0, 0);
            uint2 pk;
            pk.x = (u32)f2bf(fmaxf(acc[0], 0.f)) | ((u32)f2bf(fmaxf(acc[1], 0.f)) << 16);
            pk.y = (u32)f2bf(fmaxf(acc[2], 0.f)) | ((u32)f2bf(fmaxf(acc[3], 0.f)) << 16);
            *(uint2*)(t1S + ((size_t)((n2 * 16 + mt1) * 64 + dl) * 8 + toff)) = pk;
        }
    }
    __syncthreads();

    // ---- GEMM2 (32x32x16): T2^T = W2^T(256x256) @ T1^T(256x|act|)
    // wave w owns m-tile w (32 h_out rows); a2[16] persistent (64 VGPR)
    bf16x8 a2[16];
#pragma unroll
    for (int ks = 0; ks < 16; ++ks)
        a2[ks] = *(const bf16x8*)(w2t + ((size_t)((l * 16 + ks) * 8 + w) * 64 + lane) * 8);

    float ms[16];
#pragma unroll
    for (int r = 0; r < 16; ++r) ms[r] = 0.f;
    int rbase = w * 32 + 4 * (lane >> 5);
    for (int n2 = 0; n2 < NT2; ++n2) {
        f32x16 acc = {0.f};
#pragma unroll
        for (int kt = 0; kt < 16; ++kt) {
            bf16x8 bt = *(const bf16x8*)(t1S + ((size_t)(n2 * 16 + kt) * 64 + lane) * 8);
            acc = __builtin_amdgcn_mfma_f32_32x32x16_bf16(a2[kt], bt, acc, 0, 0, 0);
        }
        float aw = (n2 * 32 + (lane & 31)) < cnt ? 1.f : 0.f;
#pragma unroll
        for (int r = 0; r < 16; ++r) {
            float bvv = b2S[rbase + (r & 3) + 8 * (r >> 2)];
            ms[r] += fmaxf(acc[r] + bvv, 0.f) * aw;
        }
    }
#pragma unroll
    for (int r = 0; r < 16; ++r) {
        ms[r] += __shfl_xor(ms[r], 1);
        ms[r] += __shfl_xor(ms[r], 2);
        ms[r] += __shfl_xor(ms[r], 4);
        ms[r] += __shfl_xor(ms[r], 8);
        ms[r] += __shfl_xor(ms[r], 16);
    }
    if ((lane & 31) == 0) {
#pragma unroll
        for (int g = 0; g < 4; ++g) {
            f32x4 o = {ms[g * 4], ms[g * 4 + 1], ms[g * 4 + 2], ms[g * 4 + 3]};
            *(f32x4*)(&msgS[rbase + g * 8]) = o;
        }
    }
    __syncthreads();

    // ---- tail: residual + mask; emit bf16 rows (LN'd or raw) for next stage
    float v = 0.f;
    if (tid < 256) {
        float mv = (float)mask[row];
        v = (h[(size_t)row * 256 + tid] + msgS[tid]) * mv;
        h[(size_t)row * 256 + tid] = v;
    }
    float s = v, s2 = v * v;
#pragma unroll
    for (int off = 32; off; off >>= 1) {
        s  += __shfl_xor(s,  off);
        s2 += __shfl_xor(s2, off);
    }
    if (lane == 0) { rs[w] = s; rs2[w] = s2; }
    __syncthreads();
    if (tid < 256) {
        float o;
        if (doLN) {
            float S = 0.f, S2 = 0.f;
#pragma unroll
            for (int t = 0; t < 8; ++t) { S += rs[t]; S2 += rs2[t]; }
            float mu  = S * (1.f / 256.f);
            float var = S2 * (1.f / 256.f) - mu * mu;
            float rstd = rsqrtf(var + 1e-5f);
            o = (v - mu) * rstd * lngN[tid] + lnbN[tid];
        } else o = v;
        hnbf[(size_t)row * 256 + tid] = f2bf(o);
    }
}

// ---------------- readout ----------------

// scores = tanh(h@pW+pb)@aW + ab via MFMA on raw bf16 h rows.  grid: 8 x 512
__global__ __launch_bounds__(512) void k_ro1(const u16* __restrict__ hbf,
        const u16* __restrict__ pwt, const float* __restrict__ pb,
        const float* __restrict__ aW, const float* __restrict__ ab,
        float* __restrict__ scores) {
    int b = blockIdx.x;
    int tid = threadIdx.x, w = tid >> 6, lane = tid & 63;
    f32x4 acc[16];
#pragma unroll
    for (int mt = 0; mt < 16; ++mt)
        acc[mt] = *(const f32x4*)(pb + mt * 16 + (lane >> 4) * 4);
#pragma unroll
    for (int kt = 0; kt < 8; ++kt) {
        bf16x8 bt = *(const bf16x8*)(hbf + ((size_t)(b * 128 + w * 16 + (lane & 15)) * 256 + kt * 32 + (lane >> 4) * 8));
#pragma unroll
        for (int mt = 0; mt < 16; ++mt) {
            bf16x8 a = *(const bf16x8*)(pwt + ((size_t)(kt * 16 + mt) * 64 + lane) * 8);
            acc[mt] = __builtin_amdgcn_mfma_f32_16x16x32_bf16(a, bt, acc[mt], 0, 0, 0);
        }
    }
    float sc = 0.f;
#pragma unroll
    for (int mt = 0; mt < 16; ++mt) {
#pragma unroll
        for (int r = 0; r < 4; ++r)
            sc += tanhf(acc[mt][r]) * aW[mt * 16 + (lane >> 4) * 4 + r];
    }
    sc += __shfl_xor(sc, 16);
    sc += __shfl_xor(sc, 32);
    if (lane < 16) scores[b * 128 + w * 16 + lane] = sc + ab[0];
}

__global__ void k_ro2(const float* __restrict__ h, const float* __restrict__ scores,
                      const int* __restrict__ mask, const float* __restrict__ phW,
                      const float* __restrict__ phb, float* __restrict__ out) {
    __shared__ float aS[128];
    __shared__ float rm[4], rc[4], red[4];
    int b = blockIdx.x, tid = threadIdx.x, w = tid >> 6, lane = tid & 63;
    float mv = 0.f, sv = -__builtin_inff();
    if (tid < 128) {
        mv = (float)mask[b * 128 + tid];
        if (mv > 0.f) sv = scores[b * 128 + tid];
    }
    float mx = sv, cs = mv;
#pragma unroll
    for (int off = 32; off; off >>= 1) {
        mx = fmaxf(mx, __shfl_xor(mx, off));
        cs += __shfl_xor(cs, off);
    }
    if (lane == 0) { rm[w] = mx; rc[w] = cs; }
    __syncthreads();
    mx = fmaxf(fmaxf(rm[0], rm[1]), fmaxf(rm[2], rm[3]));
    float cnt = rc[0] + rc[1] + rc[2] + rc[3];
    float e = (tid < 128 && mv > 0.f) ? expf(sv - mx) : 0.f;
    float se = e;
#pragma unroll
    for (int off = 32; off; off >>= 1) se += __shfl_xor(se, off);
    if (lane == 0) red[w] = se;
    __syncthreads();
    float S = red[0] + red[1] + red[2] + red[3];
    if (tid < 128) {
        float a;
        if (S > 0.f) a = e / S;
        else         a = (mv > 0.f) ? 1.f / fmaxf(cnt, 1.f) : 0.f;
        aS[tid] = a;
    }
    __syncthreads();
    float g = 0.f;
    const float* hb = h + (size_t)b * 128 * 256;
    for (int n = 0; n < 128; ++n) g += aS[n] * hb[(size_t)n * 256 + tid];
    float p = g * phW[tid];
#pragma unroll
    for (int off = 32; off; off >>= 1) p += __shfl_xor(p, off);
    __syncthreads();
    if (lane == 0) red[w] = p;
    __syncthreads();
    if (tid == 0) out[b] = red[0] + red[1] + red[2] + red[3] + phb[0];
}

// ---------------- host ----------------
extern "C" void kernel_launch(void* const* d_in, const int* in_sizes, int n_in,
                              void* d_out, int out_size, void* d_ws, size_t ws_size,
                              hipStream_t stream) {
    const float* x    = (const float*)d_in[0];
    const int*   adj  = (const int*)  d_in[1];
    const float* ea   = (const float*)d_in[2];
    const int*   mask = (const int*)  d_in[3];
    const float* nW   = (const float*)d_in[4];
    const float* nb   = (const float*)d_in[5];
    const float* eW   = (const float*)d_in[6];
    const float* eb   = (const float*)d_in[7];
    const float* lng  = (const float*)d_in[8];
    const float* lnb  = (const float*)d_in[9];
    const float* W1   = (const float*)d_in[10];
    const float* b1   = (const float*)d_in[11];
    const float* W2   = (const float*)d_in[12];
    const float* b2   = (const float*)d_in[13];
    const float* ropW = (const float*)d_in[14];
    const float* ropb = (const float*)d_in[15];
    const float* roaW = (const float*)d_in[16];
    const float* roab = (const float*)d_in[17];
    const float* phW  = (const float*)d_in[18];
    const float* phb  = (const float*)d_in[19];
    float* out = (float*)d_out;

    char* p = (char*)d_ws;
    auto alloc = [&](size_t bytes) { char* r = p; p += (bytes + 255) & ~(size_t)255; return r; };
    float* h     = (float*)alloc((size_t)8 * 128 * 256 * 4);
    u16*   hnbf  = (u16*)  alloc((size_t)8 * 128 * 256 * 2);
    float* hn1p  = (float*)alloc((size_t)8 * 32768 * 4);
    u16*   ef    = (u16*)  alloc((size_t)8 * 128 * 4096 * 2);
    u16*   wf1t  = (u16*)  alloc((size_t)8 * 16 * 64 * 8 * 2);
    u16*   w1t   = (u16*)  alloc((size_t)8 * 8 * 16 * 64 * 8 * 2);
    u16*   w2t   = (u16*)  alloc((size_t)8 * 16 * 8 * 64 * 8 * 2);
    u16*   pwt   = (u16*)  alloc((size_t)8 * 16 * 64 * 8 * 2);
    float* bias1 = (float*)alloc((size_t)8 * 256 * 4);
    float* scores= (float*)alloc((size_t)1024 * 4);

    k_h0ln    <<<1024, 256, 0, stream>>>(x, nW, nb, mask, lng, lnb, h, hnbf);
    k_edgefrag<<<2048, 256, 0, stream>>>(ea, ef);
    k_wt      <<<256,  256, 0, stream>>>(W1, w1t);
    k_w2t32   <<<256,  256, 0, stream>>>(W2, w2t);
    k_wf1b    <<<8,    256, 0, stream>>>(eW, eb, W1, b1, wf1t, bias1);
    k_pwt     <<<32,   256, 0, stream>>>(ropW, pwt);

    for (int l = 0; l < 8; ++l) {
        k_hn1<<<128,  256, 0, stream>>>(w1t, hnbf, bias1, hn1p, l);
        int doLN = (l < 7) ? 1 : 0;
        int ln_next = (l < 7) ? (l + 1) : l;
        k_msg<<<1024, 512, 0, stream>>>(wf1t, ef, w2t, hn1p, b2, adj, mask, h,
                                        lng + ln_next * 256, lnb + ln_next * 256,
                                        hnbf, l, doLN);
    }

    k_ro1<<<8,   512, 0, stream>>>(hnbf, pwt, ropb, roaW, roab, scores);
    k_ro2<<<8,   256, 0, stream>>>(h, scores, mask, phW, phb, out);
}

// Round 7
// 377.189 us; speedup vs baseline: 2.2375x; 1.1022x over previous
//
#include <hip/hip_runtime.h>

// ---------------- common ----------------
typedef float  f32x4   __attribute__((ext_vector_type(4)));
typedef short  bf16x8  __attribute__((ext_vector_type(8)));
typedef unsigned short u16;
typedef unsigned int   u32;

static __device__ __forceinline__ u16 f2bf(float f) {   // RNE float -> bf16
    u32 u = __float_as_uint(f);
    u += 0x7FFFu + ((u >> 16) & 1u);
    return (u16)(u >> 16);
}

// dims: B=8 N=128 F_IN=64 F_E=16 H=256 L=8

// ---------------- setup kernels ----------------

// h0 = x @ node_W + node_b, then mask + layernorm(l=0) -> bf16.  grid: 1024 x 256
__global__ void k_h0ln(const float* __restrict__ x, const float* __restrict__ nW,
                       const float* __restrict__ nb, const int* __restrict__ mask,
                       const float* __restrict__ lng, const float* __restrict__ lnb,
                       float* __restrict__ h, u16* __restrict__ hnbf) {
    __shared__ float xr[64];
    __shared__ float rs[4], rs2[4];
    int row = blockIdx.x, c = threadIdx.x;
    if (c < 64) xr[c] = x[row * 64 + c];
    __syncthreads();
    float acc = nb[c];
#pragma unroll
    for (int k = 0; k < 64; ++k) acc += xr[k] * nW[k * 256 + c];
    float mv = (float)mask[row];
    float v = acc * mv;
    h[row * 256 + c] = v;
    float s = v, s2 = v * v;
    int w = c >> 6, lane = c & 63;
#pragma unroll
    for (int off = 32; off; off >>= 1) {
        s  += __shfl_xor(s,  off);
        s2 += __shfl_xor(s2, off);
    }
    if (lane == 0) { rs[w] = s; rs2[w] = s2; }
    __syncthreads();
    float S  = rs[0] + rs[1] + rs[2] + rs[3];
    float S2 = rs2[0] + rs2[1] + rs2[2] + rs2[3];
    float mu  = S * (1.f / 256.f);
    float var = S2 * (1.f / 256.f) - mu * mu;
    float rstd = rsqrtf(var + 1e-5f);
    hnbf[row * 256 + c] = f2bf((v - mu) * rstd * lng[c] + lnb[c]);
}

// edge_attr -> bf16 fragment layout (16x16x32 B), K padded 16->32 with zeros.
// ef[((b*128+i)*8 + nt)*64 + lane][8]   j = nt*16+(lane&15), k0=(lane>>4)*8
__global__ void k_edgefrag(const float* __restrict__ ea, u16* __restrict__ ef) {
    int gid = blockIdx.x * 256 + threadIdx.x;
    int lane = gid & 63, nt = (gid >> 6) & 7, i = (gid >> 9) & 127, b = gid >> 16;
    int j = nt * 16 + (lane & 15), k0 = (lane >> 4) * 8;
    uint4 out = {0u, 0u, 0u, 0u};
    if (k0 < 16) {
        const float* p = ea + (((size_t)(b * 128 + i) * 128 + j) * 16 + k0);
        u16 us[8];
#pragma unroll
        for (int t = 0; t < 8; ++t) us[t] = f2bf(p[t]);
        out.x = (u32)us[0] | ((u32)us[1] << 16);
        out.y = (u32)us[2] | ((u32)us[3] << 16);
        out.z = (u32)us[4] | ((u32)us[5] << 16);
        out.w = (u32)us[6] | ((u32)us[7] << 16);
    }
    ((uint4*)ef)[gid] = out;
}

// W1^T / W2^T fragment packs (16x16x32 A): wt[((l*8+kt)*16+mt)*64+lane][8]
__global__ void k_wt(const float* __restrict__ W1, const float* __restrict__ W2,
                     u16* __restrict__ w1t, u16* __restrict__ w2t) {
    int gid = blockIdx.x * 256 + threadIdx.x;
    int lane = gid & 63, mt = (gid >> 6) & 15, kt = (gid >> 10) & 7, l = gid >> 13;
    int hh = mt * 16 + (lane & 15), k = kt * 32 + (lane >> 4) * 8;
    u16 a[8], b[8];
#pragma unroll
    for (int t = 0; t < 8; ++t) {
        size_t idx = (size_t)l * 65536 + (size_t)(k + t) * 256 + hh;
        a[t] = f2bf(W1[idx]);
        b[t] = f2bf(W2[idx]);
    }
    uint4 oa, ob;
    oa.x = (u32)a[0] | ((u32)a[1] << 16); oa.y = (u32)a[2] | ((u32)a[3] << 16);
    oa.z = (u32)a[4] | ((u32)a[5] << 16); oa.w = (u32)a[6] | ((u32)a[7] << 16);
    ob.x = (u32)b[0] | ((u32)b[1] << 16); ob.y = (u32)b[2] | ((u32)b[3] << 16);
    ob.z = (u32)b[4] | ((u32)b[5] << 16); ob.w = (u32)b[6] | ((u32)b[7] << 16);
    ((uint4*)w1t)[gid] = oa;
    ((uint4*)w2t)[gid] = ob;
}

// ro_pW^T fragment pack (16x16x32 A): pwt[(kt*16+mt)*64+lane][8]
__global__ void k_pwt(const float* __restrict__ pW, u16* __restrict__ pwt) {
    int gid = blockIdx.x * 256 + threadIdx.x;
    int lane = gid & 63, mt = (gid >> 6) & 15, kt = gid >> 10;
    int hh = mt * 16 + (lane & 15), k = kt * 32 + (lane >> 4) * 8;
    u16 a[8];
#pragma unroll
    for (int t = 0; t < 8; ++t) a[t] = f2bf(pW[(size_t)(k + t) * 256 + hh]);
    uint4 o;
    o.x = (u32)a[0] | ((u32)a[1] << 16); o.y = (u32)a[2] | ((u32)a[3] << 16);
    o.z = (u32)a[4] | ((u32)a[5] << 16); o.w = (u32)a[6] | ((u32)a[7] << 16);
    ((uint4*)pwt)[gid] = o;
}

// Wf1 = edge_W @ W1[l] (A-fragment pack) AND bias1 = edge_b @ W1[l] + b1[l]
__global__ void k_wf1b(const float* __restrict__ eW, const float* __restrict__ eb,
                       const float* __restrict__ W1, const float* __restrict__ b1,
                       u16* __restrict__ wf, float* __restrict__ bias1) {
    __shared__ float eWsT[256 * 16];   // [c][k]
    __shared__ float ebS[256];
    int l = blockIdx.x, tid = threadIdx.x;
#pragma unroll
    for (int k = 0; k < 16; ++k) eWsT[tid * 16 + k] = eW[k * 256 + tid];
    ebS[tid] = eb[tid];
    __syncthreads();
    float acc[16];
#pragma unroll
    for (int k = 0; k < 16; ++k) acc[k] = 0.f;
    float bacc = b1[l * 256 + tid];
    const float* w1c = W1 + (size_t)l * 65536 + tid;
    for (int c = 0; c < 256; ++c) {
        float wv = w1c[(size_t)c * 256];
        const f32x4* e = (const f32x4*)&eWsT[c * 16];
#pragma unroll
        for (int q = 0; q < 4; ++q) {
            f32x4 ev = e[q];
#pragma unroll
            for (int t = 0; t < 4; ++t) acc[q * 4 + t] += ev[t] * wv;
        }
        bacc += ebS[c] * wv;
    }
    bias1[l * 256 + tid] = bacc;
    int mt = tid >> 4, lo = tid & 15;
#pragma unroll
    for (int c4 = 0; c4 < 4; ++c4) {
        u16 us[8];
#pragma unroll
        for (int t = 0; t < 8; ++t) {
            int k = c4 * 8 + t;
            us[t] = (k < 16) ? f2bf(acc[k]) : (u16)0;
        }
        uint4 o;
        o.x = (u32)us[0] | ((u32)us[1] << 16);
        o.y = (u32)us[2] | ((u32)us[3] << 16);
        o.z = (u32)us[4] | ((u32)us[5] << 16);
        o.w = (u32)us[6] | ((u32)us[7] << 16);
        ((uint4*)wf)[(size_t)(l * 16 + mt) * 64 + c4 * 16 + lo] = o;
    }
}

// ---------------- per-layer kernels ----------------

// hn1' = h_norm @ W1[l] + bias1[l] (transposed, 16x16 fragment-permuted output)
// grid: 128 x 256  (block = (b, mt))
__global__ __launch_bounds__(256) void k_hn1(const u16* __restrict__ w1t,
        const u16* __restrict__ hnbf, const float* __restrict__ bias1,
        float* __restrict__ hn1p, int l) {
    int orig = blockIdx.x;
    int bid = (orig & 7) * 16 + (orig >> 3);      // XCD swizzle
    int b = bid >> 4, mt = bid & 15;
    int tid = threadIdx.x, w = tid >> 6, lane = tid & 63;
    f32x4 bv = *(const f32x4*)(bias1 + l * 256 + mt * 16 + (lane >> 4) * 4);
    f32x4 acc0 = bv, acc1 = bv;
    int j0 = (w * 2) * 16 + (lane & 15), j1 = j0 + 16;
#pragma unroll
    for (int kt = 0; kt < 8; ++kt) {
        bf16x8 a = *(const bf16x8*)(w1t + ((size_t)((l * 8 + kt) * 16 + mt) * 64 + lane) * 8);
        bf16x8 bt0 = *(const bf16x8*)(hnbf + ((size_t)(b * 128 + j0) * 256 + kt * 32 + (lane >> 4) * 8));
        bf16x8 bt1 = *(const bf16x8*)(hnbf + ((size_t)(b * 128 + j1) * 256 + kt * 32 + (lane >> 4) * 8));
        acc0 = __builtin_amdgcn_mfma_f32_16x16x32_bf16(a, bt0, acc0, 0, 0, 0);
        acc1 = __builtin_amdgcn_mfma_f32_16x16x32_bf16(a, bt1, acc1, 0, 0, 0);
    }
    float* outb = hn1p + (size_t)b * 32768;
    *(f32x4*)(outb + ((size_t)(mt * 8 + w * 2) * 64 + lane) * 4)     = acc0;
    *(f32x4*)(outb + ((size_t)(mt * 8 + w * 2 + 1) * 64 + lane) * 4) = acc1;
}

// money kernel: GEMM1 over ALL j-tiles with coalesced loads, rank-compacted
// scatter into t1S; stale tail ranks zeroed; GEMM2 on compacted tiles only.
// grid: 1024 x 512, 2 blocks/CU
__global__ __launch_bounds__(512, 4) void k_msg(
        const u16* __restrict__ wf1t, const u16* __restrict__ ef,
        const u16* __restrict__ w2t,  const float* __restrict__ hn1p,
        const float* __restrict__ b2, const int* __restrict__ adj,
        const int* __restrict__ mask, float* __restrict__ h,
        const float* __restrict__ lngN, const float* __restrict__ lnbN,
        u16* __restrict__ hnbf, int l, int doLN) {

    __shared__ __align__(16) u16  t1S[8 * 8 * 64 * 8];   // 64 KiB [kt][n][64][8]
    __shared__ __align__(16) float b2S[256];
    __shared__ __align__(16) float msgS[256];
    __shared__ int rankS[128];    // j -> compact rank, -1 if inactive
    __shared__ int cntS;
    __shared__ float rs[8], rs2[8];

    int orig = blockIdx.x;
    int bid = (orig & 7) * 128 + (orig >> 3);     // XCD swizzle
    int b = bid >> 7, i = bid & 127;
    int tid = threadIdx.x, w = tid >> 6, lane = tid & 63;
    int row = b * 128 + i;

    if (tid < 256) b2S[tid] = b2[l * 256 + tid];
    if (w == 0) {   // rank = order-preserving prefix count of active j
        int f0 = adj[(size_t)row * 128 + lane] != 0;
        int f1 = adj[(size_t)row * 128 + 64 + lane] != 0;
        unsigned long long m0 = __ballot(f0);
        unsigned long long m1 = __ballot(f1);
        unsigned long long lt = (1ull << lane) - 1ull;
        int c0 = __popcll(m0);
        rankS[lane]      = f0 ? __popcll(m0 & lt)      : -1;
        rankS[64 + lane] = f1 ? c0 + __popcll(m1 & lt) : -1;
        if (lane == 0) cntS = c0 + __popcll(m1);
    }
    __syncthreads();
    int cnt = cntS;
    int NT = (cnt + 15) >> 4;

    // ---- zero stale tail ranks [cnt, NT*16) in this wave's kt-chunk (= w)
    {
        int c = cnt + (lane >> 2);
        int kg = lane & 3;
        if (c < NT * 16) {
            uint4 z = {0u, 0u, 0u, 0u};
            *(uint4*)(t1S + ((size_t)((w * 8 + (c >> 4)) * 64 + kg * 16 + (c & 15)) * 8)) = z;
        }
    }

    // ---- GEMM1: all 8 j-tiles, coalesced; write compacted by rank.
    // wave w owns mt {2w, 2w+1}; t1S kt-chunk = w for both.
    const u16*  efb = ef + (size_t)row * 4096;
    const float* hpb = hn1p + (size_t)b * 32768;
    int mt0 = w * 2, mt1 = w * 2 + 1;
    bf16x8 aG0 = *(const bf16x8*)(wf1t + ((size_t)(l * 16 + mt0) * 64 + lane) * 8);
    bf16x8 aG1 = *(const bf16x8*)(wf1t + ((size_t)(l * 16 + mt1) * 64 + lane) * 8);
    int g0   = (lane >> 5) * 16;          // slot offset for mt0
    int g1   = 32 + g0;                   // slot offset for mt1
    int toff = ((lane >> 4) & 1) * 4;     // u16 offset within slot
#pragma unroll
    for (int nt = 0; nt < 8; ++nt) {
        bf16x8 be = *(const bf16x8*)(efb + (size_t)(nt * 64 + lane) * 8);
        int r = rankS[nt * 16 + (lane & 15)];
        f32x4 ci0 = *(const f32x4*)(hpb + ((size_t)(mt0 * 8 + nt) * 64 + lane) * 4);
        f32x4 acc0 = __builtin_amdgcn_mfma_f32_16x16x32_bf16(aG0, be, ci0, 0, 0, 0);
        f32x4 ci1 = *(const f32x4*)(hpb + ((size_t)(mt1 * 8 + nt) * 64 + lane) * 4);
        f32x4 acc1 = __builtin_amdgcn_mfma_f32_16x16x32_bf16(aG1, be, ci1, 0, 0, 0);
        if (r >= 0) {
            int base = (w * 8 + (r >> 4)) * 64 + (r & 15);
            uint2 pk0, pk1;
            pk0.x = (u32)f2bf(fmaxf(acc0[0], 0.f)) | ((u32)f2bf(fmaxf(acc0[1], 0.f)) << 16);
            pk0.y = (u32)f2bf(fmaxf(acc0[2], 0.f)) | ((u32)f2bf(fmaxf(acc0[3], 0.f)) << 16);
            pk1.x = (u32)f2bf(fmaxf(acc1[0], 0.f)) | ((u32)f2bf(fmaxf(acc1[1], 0.f)) << 16);
            pk1.y = (u32)f2bf(fmaxf(acc1[2], 0.f)) | ((u32)f2bf(fmaxf(acc1[3], 0.f)) << 16);
            *(uint2*)(t1S + ((size_t)(base + g0)) * 8 + toff) = pk0;
            *(uint2*)(t1S + ((size_t)(base + g1)) * 8 + toff) = pk1;
        }
    }
    __syncthreads();

    // ---- GEMM2: T2^T = W2^T(256x256) @ T1^T(256x|act|); persistent a2[8][2]
    bf16x8 a2[8][2];
#pragma unroll
    for (int kt = 0; kt < 8; ++kt) {
        a2[kt][0] = *(const bf16x8*)(w2t + ((size_t)((l * 8 + kt) * 16 + mt0) * 64 + lane) * 8);
        a2[kt][1] = *(const bf16x8*)(w2t + ((size_t)((l * 8 + kt) * 16 + mt1) * 64 + lane) * 8);
    }
    int hb0 = mt0 * 16 + (lane >> 4) * 4;
    int hb1 = mt1 * 16 + (lane >> 4) * 4;
    f32x4 bv0 = *(const f32x4*)(&b2S[hb0]);
    f32x4 bv1 = *(const f32x4*)(&b2S[hb1]);
    f32x4 ms0 = (f32x4){0.f, 0.f, 0.f, 0.f};
    f32x4 ms1 = (f32x4){0.f, 0.f, 0.f, 0.f};
    for (int n = 0; n < NT; ++n) {
        f32x4 acc0 = (f32x4){0.f, 0.f, 0.f, 0.f};
        f32x4 acc1 = (f32x4){0.f, 0.f, 0.f, 0.f};
#pragma unroll
        for (int kt = 0; kt < 8; ++kt) {
            bf16x8 bt = *(const bf16x8*)(t1S + ((size_t)(kt * 8 + n) * 64 + lane) * 8);
            acc0 = __builtin_amdgcn_mfma_f32_16x16x32_bf16(a2[kt][0], bt, acc0, 0, 0, 0);
            acc1 = __builtin_amdgcn_mfma_f32_16x16x32_bf16(a2[kt][1], bt, acc1, 0, 0, 0);
        }
        bool ok = (n * 16 + (lane & 15)) < cnt;   // select (not multiply):
#pragma unroll                                    // garbage can never reach ms
        for (int r = 0; r < 4; ++r) {
            ms0[r] += ok ? fmaxf(acc0[r] + bv0[r], 0.f) : 0.f;
            ms1[r] += ok ? fmaxf(acc1[r] + bv1[r], 0.f) : 0.f;
        }
    }
#pragma unroll
    for (int r = 0; r < 4; ++r) {
        ms0[r] += __shfl_xor(ms0[r], 1); ms1[r] += __shfl_xor(ms1[r], 1);
        ms0[r] += __shfl_xor(ms0[r], 2); ms1[r] += __shfl_xor(ms1[r], 2);
        ms0[r] += __shfl_xor(ms0[r], 4); ms1[r] += __shfl_xor(ms1[r], 4);
        ms0[r] += __shfl_xor(ms0[r], 8); ms1[r] += __shfl_xor(ms1[r], 8);
    }
    if ((lane & 15) == 0) {
        *(f32x4*)(&msgS[hb0]) = ms0;
        *(f32x4*)(&msgS[hb1]) = ms1;
    }
    __syncthreads();

    // ---- tail: residual + mask; emit bf16 rows (LN'd or raw) for next stage
    float v = 0.f;
    if (tid < 256) {
        float mv = (float)mask[row];
        v = (h[(size_t)row * 256 + tid] + msgS[tid]) * mv;
        h[(size_t)row * 256 + tid] = v;
    }
    float s = v, s2 = v * v;
#pragma unroll
    for (int off = 32; off; off >>= 1) {
        s  += __shfl_xor(s,  off);
        s2 += __shfl_xor(s2, off);
    }
    if (lane == 0) { rs[w] = s; rs2[w] = s2; }
    __syncthreads();
    if (tid < 256) {
        float o;
        if (doLN) {
            float S = 0.f, S2 = 0.f;
#pragma unroll
            for (int t = 0; t < 8; ++t) { S += rs[t]; S2 += rs2[t]; }
            float mu  = S * (1.f / 256.f);
            float var = S2 * (1.f / 256.f) - mu * mu;
            float rstd = rsqrtf(var + 1e-5f);
            o = (v - mu) * rstd * lngN[tid] + lnbN[tid];
        } else o = v;
        hnbf[(size_t)row * 256 + tid] = f2bf(o);
    }
}

// ---------------- readout ----------------

// scores = tanh(h@pW+pb)@aW + ab via MFMA on raw bf16 h rows.  grid: 8 x 512
__global__ __launch_bounds__(512) void k_ro1(const u16* __restrict__ hbf,
        const u16* __restrict__ pwt, const float* __restrict__ pb,
        const float* __restrict__ aW, const float* __restrict__ ab,
        float* __restrict__ scores) {
    int b = blockIdx.x;
    int tid = threadIdx.x, w = tid >> 6, lane = tid & 63;
    f32x4 acc[16];
#pragma unroll
    for (int mt = 0; mt < 16; ++mt)
        acc[mt] = *(const f32x4*)(pb + mt * 16 + (lane >> 4) * 4);
#pragma unroll
    for (int kt = 0; kt < 8; ++kt) {
        bf16x8 bt = *(const bf16x8*)(hbf + ((size_t)(b * 128 + w * 16 + (lane & 15)) * 256 + kt * 32 + (lane >> 4) * 8));
#pragma unroll
        for (int mt = 0; mt < 16; ++mt) {
            bf16x8 a = *(const bf16x8*)(pwt + ((size_t)(kt * 16 + mt) * 64 + lane) * 8);
            acc[mt] = __builtin_amdgcn_mfma_f32_16x16x32_bf16(a, bt, acc[mt], 0, 0, 0);
        }
    }
    float sc = 0.f;
#pragma unroll
    for (int mt = 0; mt < 16; ++mt) {
#pragma unroll
        for (int r = 0; r < 4; ++r)
            sc += tanhf(acc[mt][r]) * aW[mt * 16 + (lane >> 4) * 4 + r];
    }
    sc += __shfl_xor(sc, 16);
    sc += __shfl_xor(sc, 32);
    if (lane < 16) scores[b * 128 + w * 16 + lane] = sc + ab[0];
}

__global__ void k_ro2(const float* __restrict__ h, const float* __restrict__ scores,
                      const int* __restrict__ mask, const float* __restrict__ phW,
                      const float* __restrict__ phb, float* __restrict__ out) {
    __shared__ float aS[128];
    __shared__ float rm[4], rc[4], red[4];
    int b = blockIdx.x, tid = threadIdx.x, w = tid >> 6, lane = tid & 63;
    float mv = 0.f, sv = -__builtin_inff();
    if (tid < 128) {
        mv = (float)mask[b * 128 + tid];
        if (mv > 0.f) sv = scores[b * 128 + tid];
    }
    float mx = sv, cs = mv;
#pragma unroll
    for (int off = 32; off; off >>= 1) {
        mx = fmaxf(mx, __shfl_xor(mx, off));
        cs += __shfl_xor(cs, off);
    }
    if (lane == 0) { rm[w] = mx; rc[w] = cs; }
    __syncthreads();
    mx = fmaxf(fmaxf(rm[0], rm[1]), fmaxf(rm[2], rm[3]));
    float cnt = rc[0] + rc[1] + rc[2] + rc[3];
    float e = (tid < 128 && mv > 0.f) ? expf(sv - mx) : 0.f;
    float se = e;
#pragma unroll
    for (int off = 32; off; off >>= 1) se += __shfl_xor(se, off);
    if (lane == 0) red[w] = se;
    __syncthreads();
    float S = red[0] + red[1] + red[2] + red[3];
    if (tid < 128) {
        float a;
        if (S > 0.f) a = e / S;
        else         a = (mv > 0.f) ? 1.f / fmaxf(cnt, 1.f) : 0.f;
        aS[tid] = a;
    }
    __syncthreads();
    float g = 0.f;
    const float* hb = h + (size_t)b * 128 * 256;
    for (int n = 0; n < 128; ++n) g += aS[n] * hb[(size_t)n * 256 + tid];
    float p = g * phW[tid];
#pragma unroll
    for (int off = 32; off; off >>= 1) p += __shfl_xor(p, off);
    __syncthreads();
    if (lane == 0) red[w] = p;
    __syncthreads();
    if (tid == 0) out[b] = red[0] + red[1] + red[2] + red[3] + phb[0];
}

// ---------------- host ----------------
extern "C" void kernel_launch(void* const* d_in, const int* in_sizes, int n_in,
                              void* d_out, int out_size, void* d_ws, size_t ws_size,
                              hipStream_t stream) {
    const float* x    = (const float*)d_in[0];
    const int*   adj  = (const int*)  d_in[1];
    const float* ea   = (const float*)d_in[2];
    const int*   mask = (const int*)  d_in[3];
    const float* nW   = (const float*)d_in[4];
    const float* nb   = (const float*)d_in[5];
    const float* eW   = (const float*)d_in[6];
    const float* eb   = (const float*)d_in[7];
    const float* lng  = (const float*)d_in[8];
    const float* lnb  = (const float*)d_in[9];
    const float* W1   = (const float*)d_in[10];
    const float* b1   = (const float*)d_in[11];
    const float* W2   = (const float*)d_in[12];
    const float* b2   = (const float*)d_in[13];
    const float* ropW = (const float*)d_in[14];
    const float* ropb = (const float*)d_in[15];
    const float* roaW = (const float*)d_in[16];
    const float* roab = (const float*)d_in[17];
    const float* phW  = (const float*)d_in[18];
    const float* phb  = (const float*)d_in[19];
    float* out = (float*)d_out;

    char* p = (char*)d_ws;
    auto alloc = [&](size_t bytes) { char* r = p; p += (bytes + 255) & ~(size_t)255; return r; };
    float* h     = (float*)alloc((size_t)8 * 128 * 256 * 4);
    u16*   hnbf  = (u16*)  alloc((size_t)8 * 128 * 256 * 2);
    float* hn1p  = (float*)alloc((size_t)8 * 32768 * 4);
    u16*   ef    = (u16*)  alloc((size_t)8 * 128 * 4096 * 2);
    u16*   wf1t  = (u16*)  alloc((size_t)8 * 16 * 64 * 8 * 2);
    u16*   w1t   = (u16*)  alloc((size_t)8 * 8 * 16 * 64 * 8 * 2);
    u16*   w2t   = (u16*)  alloc((size_t)8 * 8 * 16 * 64 * 8 * 2);
    u16*   pwt   = (u16*)  alloc((size_t)8 * 16 * 64 * 8 * 2);
    float* bias1 = (float*)alloc((size_t)8 * 256 * 4);
    float* scores= (float*)alloc((size_t)1024 * 4);

    k_h0ln    <<<1024, 256, 0, stream>>>(x, nW, nb, mask, lng, lnb, h, hnbf);
    k_edgefrag<<<2048, 256, 0, stream>>>(ea, ef);
    k_wt      <<<256,  256, 0, stream>>>(W1, W2, w1t, w2t);
    k_wf1b    <<<8,    256, 0, stream>>>(eW, eb, W1, b1, wf1t, bias1);
    k_pwt     <<<32,   256, 0, stream>>>(ropW, pwt);

    for (int l = 0; l < 8; ++l) {
        k_hn1<<<128,  256, 0, stream>>>(w1t, hnbf, bias1, hn1p, l);
        int doLN = (l < 7) ? 1 : 0;
        int ln_next = (l < 7) ? (l + 1) : l;
        k_msg<<<1024, 512, 0, stream>>>(wf1t, ef, w2t, hn1p, b2, adj, mask, h,
                                        lng + ln_next * 256, lnb + ln_next * 256,
                                        hnbf, l, doLN);
    }

    k_ro1<<<8,   512, 0, stream>>>(hnbf, pwt, ropb, roaW, roab, scores);
    k_ro2<<<8,   256, 0, stream>>>(h, scores, mask, phW, phb, out);
}